// Round 6
// baseline (440.334 us; speedup 1.0000x reference)
//
#include <hip/hip_runtime.h>

typedef __bf16 v8bf __attribute__((ext_vector_type(8)));
typedef __bf16 v4bf __attribute__((ext_vector_type(4)));
typedef float  v4f  __attribute__((ext_vector_type(4)));
typedef unsigned short u16;

#define LN_EPS_F 1e-5f
#define ATTN_EPS 1e-6f

static constexpr int Bsz = 32;
static constexpr int Nn  = 4096;
static constexpr int Dd  = 512;
static constexpr int Ss  = 128;
static constexpr int NSs = 8;
static constexpr int Hh  = 256;
static constexpr int MROWS = Bsz * Nn;   // 131072

__device__ __forceinline__ void load_lds16(const void* g, void* l) {
    __builtin_amdgcn_global_load_lds(
        (const __attribute__((address_space(1))) void*)g,
        (__attribute__((address_space(3))) void*)l, 16, 0, 0);
}

// ---------------------------------------------------------------------------
// Kernel 0: streaming cast X fp32 -> bf16 + per-row LN stats (mean, rstd).
// ---------------------------------------------------------------------------
__global__ __launch_bounds__(256) void k_cast(const float* __restrict__ X,
                                              u16* __restrict__ Xb,
                                              float2* __restrict__ stats) {
    const int wid = threadIdx.x >> 6, lane = threadIdx.x & 63;
    const int row = blockIdx.x * 4 + wid;
    const float4* xp = reinterpret_cast<const float4*>(X + (size_t)row * Dd) + lane * 2;
    float4 a = xp[0];
    float4 b = xp[1];
    float s  = a.x + a.y + a.z + a.w + b.x + b.y + b.z + b.w;
    float s2 = a.x*a.x + a.y*a.y + a.z*a.z + a.w*a.w
             + b.x*b.x + b.y*b.y + b.z*b.z + b.w*b.w;
    v8bf o;
    o[0] = (__bf16)a.x; o[1] = (__bf16)a.y; o[2] = (__bf16)a.z; o[3] = (__bf16)a.w;
    o[4] = (__bf16)b.x; o[5] = (__bf16)b.y; o[6] = (__bf16)b.z; o[7] = (__bf16)b.w;
    *reinterpret_cast<v8bf*>(Xb + (size_t)row * Dd + lane * 8) = o;
#pragma unroll
    for (int off = 32; off > 0; off >>= 1) {
        s  += __shfl_xor(s, off);
        s2 += __shfl_xor(s2, off);
    }
    if (lane == 0) {
        float m = s * (1.0f / Dd);
        float v = s2 * (1.0f / Dd) - m * m;
        stats[row] = make_float2(m, rsqrtf(v + LN_EPS_F));
    }
}

// ---------------------------------------------------------------------------
// Kernel 1: prep — slots init + cbv0[s] = lnb . Wv[s,:]
// ---------------------------------------------------------------------------
__global__ __launch_bounds__(256) void k_prep(const float* __restrict__ Wv,
                                              const float* __restrict__ ln_in_b,
                                              const float* __restrict__ slots_init,
                                              const float* __restrict__ mu,
                                              const float* __restrict__ lsig,
                                              float* __restrict__ cbv0,
                                              float* __restrict__ slots) {
    const int bid = blockIdx.x;
    const int t = threadIdx.x;
    if (bid < 128) {
        int idx = bid * 256 + t;                 // 32768 slot elems
        int sidx = idx & (Ss - 1);
        slots[idx] = mu[sidx] + expf(lsig[sidx]) * slots_init[idx];
    } else {                                     // bids 128..131: cbv0 (128 rows)
        const int wid = t >> 6, lane = t & 63;
        const int rowbase = (bid - 128) * 32 + wid * 8;
        const int d0 = lane * 8;
        float4 lb0 = *reinterpret_cast<const float4*>(ln_in_b + d0);
        float4 lb1 = *reinterpret_cast<const float4*>(ln_in_b + d0 + 4);
        for (int rr = 0; rr < 8; ++rr) {
            int row = rowbase + rr;
            const float* wrow = Wv + (size_t)row * Dd;
            float4 w0 = *reinterpret_cast<const float4*>(wrow + d0);
            float4 w1 = *reinterpret_cast<const float4*>(wrow + d0 + 4);
            float accb = lb0.x*w0.x + lb0.y*w0.y + lb0.z*w0.z + lb0.w*w0.w
                       + lb1.x*w1.x + lb1.y*w1.y + lb1.z*w1.z + lb1.w*w1.w;
#pragma unroll
            for (int off = 32; off > 0; off >>= 1) accb += __shfl_xor(accb, off);
            if (lane == 0) cbv0[row] = accb;
        }
    }
}

// ---------------------------------------------------------------------------
// Kernel 2: initial q = LN_slot(slots) @ Wq^T * scale.  One block per (b,m).
// ---------------------------------------------------------------------------
__global__ __launch_bounds__(128) void k_q(const float* __restrict__ slots,
                                           const float* __restrict__ lnw, const float* __restrict__ lnb,
                                           const float* __restrict__ Wq, float* __restrict__ q) {
    __shared__ float xs[128];
    __shared__ float red[4];
    const int t = threadIdx.x;
    const int bm = blockIdx.x;
    float x = slots[bm * 128 + t];
    float s = x, s2 = x * x;
#pragma unroll
    for (int off = 32; off > 0; off >>= 1) { s += __shfl_xor(s, off); s2 += __shfl_xor(s2, off); }
    const int wid = t >> 6, lane = t & 63;
    if (lane == 0) { red[wid * 2] = s; red[wid * 2 + 1] = s2; }
    __syncthreads();
    float S1 = red[0] + red[2], S2 = red[1] + red[3];
    float m = S1 * (1.f / 128.f);
    float rstd = rsqrtf(S2 * (1.f / 128.f) - m * m + LN_EPS_F);
    xs[t] = (x - m) * rstd * lnw[t] + lnb[t];
    __syncthreads();
    const float* wr = Wq + (size_t)t * 128;
    float acc = 0.f;
#pragma unroll 8
    for (int d = 0; d < 128; d += 4) {
        float4 w = *reinterpret_cast<const float4*>(wr + d);
        acc += w.x * xs[d] + w.y * xs[d + 1] + w.z * xs[d + 2] + w.w * xs[d + 3];
    }
    q[bm * 128 + t] = acc * 0.08838834764831845f;
}

// ---------------------------------------------------------------------------
// Kernel 3: wl-gen.  wl[b,m,:] = bf16(lnw * (q[b,m,:] @ Wk)), Sw = sum(wl),
// cw = lnb . (q@Wk).  Blocks (m 0..15, b); m>=8 rows zeroed.
// ---------------------------------------------------------------------------
__global__ __launch_bounds__(256) void k_wlgen(const float* __restrict__ qbuf,
                                               const float* __restrict__ Wk,
                                               const float* __restrict__ lnw,
                                               const float* __restrict__ lnb,
                                               u16* __restrict__ wl,
                                               float* __restrict__ Sw,
                                               float* __restrict__ cw) {
    const int m = blockIdx.x, b = blockIdx.y;
    const int t = threadIdx.x;
    u16* outrow = wl + ((size_t)b * 16 + m) * 512;
    if (m >= 8) {
        outrow[t] = 0; outrow[t + 256] = 0;
        if (t == 0) { Sw[b * 16 + m] = 0.f; cw[b * 16 + m] = 0.f; }
        return;
    }
    __shared__ float qsh[128];
    __shared__ float rs[4], rc[4];
    if (t < 128) qsh[t] = qbuf[(b * 8 + m) * 128 + t];
    __syncthreads();
    float acc0 = 0.f, acc1 = 0.f;
#pragma unroll 4
    for (int s = 0; s < 128; ++s) {
        float qv = qsh[s];
        acc0 += qv * Wk[(size_t)s * 512 + t];
        acc1 += qv * Wk[(size_t)s * 512 + t + 256];
    }
    float wl0 = lnw[t] * acc0, wl1 = lnw[t + 256] * acc1;
    __bf16 b0 = (__bf16)wl0, b1 = (__bf16)wl1;
    outrow[t] = __builtin_bit_cast(u16, b0);
    outrow[t + 256] = __builtin_bit_cast(u16, b1);
    float swp = (float)b0 + (float)b1;                  // bf16-rounded, matches MFMA dot
    float cwp = lnb[t] * acc0 + lnb[t + 256] * acc1;
#pragma unroll
    for (int off = 32; off > 0; off >>= 1) { swp += __shfl_xor(swp, off); cwp += __shfl_xor(cwp, off); }
    const int lane = t & 63, wv = t >> 6;
    if (lane == 0) { rs[wv] = swp; rc[wv] = cwp; }
    __syncthreads();
    if (t == 0) {
        Sw[b * 16 + m] = rs[0] + rs[1] + rs[2] + rs[3];
        cw[b * 16 + m] = rc[0] + rc[1] + rc[2] + rc[3];
    }
}

// ---------------------------------------------------------------------------
// Kernel 4: attn+z fused pass.  Per (b, ch=16): 256 n-rows.
// Subtiles of 64 rows double-buffered in LDS (XOR-swizzled via source).
// logits = MFMA(Xb, wl); softmax over 8 slots in D-layout (shfl 1/2/4,
// m>=8 masked); z[m,d] += a*rstd*Xb accumulated in registers (16/thread).
// Outputs: z_part[b,ch,8,512], A_part/cm_part[b,ch,8].
// ---------------------------------------------------------------------------
__global__ __launch_bounds__(256, 1) void k_attnz(const u16* __restrict__ Xb,
                                                  const float2* __restrict__ stats,
                                                  const u16* __restrict__ wl,
                                                  const float* __restrict__ Sw,
                                                  const float* __restrict__ cw,
                                                  float* __restrict__ z_part,
                                                  float* __restrict__ A_part,
                                                  float* __restrict__ cm_part) {
    __shared__ __bf16 xs[2][64 * 512];    // 128 KB
    __shared__ __bf16 wls[16 * 512];      // 16 KB
    __shared__ float at[64][8];           // 2 KB
    __shared__ float redA[4][8], redC[4][8];
    const int b  = blockIdx.y;
    const int ch = blockIdx.x;
    const int t  = threadIdx.x;
    const int lane = t & 63, w = t >> 6;
    const int lr = lane & 15, g = lane >> 4;
    const size_t nbase = (size_t)b * Nn + ch * 256;

    // stage wl into LDS with row-XOR swizzle (ds_write path)
    {
        int row = t >> 4;
#pragma unroll
        for (int c = 0; c < 4; ++c) {
            int s = (t & 15) * 4 + c;
            uint4 v = *reinterpret_cast<const uint4*>(wl + ((size_t)b * 16 + row) * 512 + s * 8);
            *reinterpret_cast<uint4*>(&wls[row * 512 + (s ^ (row & 7)) * 8]) = v;
        }
    }
    const float Swm = Sw[b * 16 + lr];
    const float cwm = cw[b * 16 + lr];

    const int zm = t >> 5;        // 0..7 slot owned for z
    const int ds = t & 31;        // 16-elem d-slice
    float z[16];
#pragma unroll
    for (int i = 0; i < 16; ++i) z[i] = 0.f;
    float A_acc = 0.f, C_acc = 0.f;

#define STAGE(buf, sub)                                                         \
    {                                                                           \
        _Pragma("unroll")                                                       \
        for (int i = 0; i < 16; ++i) {                                          \
            int r = w * 16 + i;                                                 \
            load_lds16(Xb + (nbase + (sub) * 64 + r) * 512 + (lane ^ (r & 7)) * 8, \
                       &xs[buf][r * 512]);                                      \
        }                                                                       \
    }

    STAGE(0, 0);
    asm volatile("s_waitcnt vmcnt(0)" ::: "memory");
    __syncthreads();

    int cur = 0;
    const v4f vzero = {0.f, 0.f, 0.f, 0.f};
#pragma unroll 1
    for (int sub = 0; sub < 4; ++sub) {
        if (sub < 3) STAGE(cur ^ 1, sub + 1);
        // ---- logits MFMA: wave w owns rows w*16..w*16+15 of the subtile
        v4f D = vzero;
        {
            const __bf16* arow = &xs[cur][(w * 16 + lr) * 512];
            const __bf16* brow = &wls[lr * 512];
            const int sw = lr & 7;              // (w*16+lr)&7 == lr&7
#pragma unroll
            for (int kk = 0; kk < 16; ++kk) {
                int sl = ((kk * 4 + g) ^ sw) * 8;
                v8bf a  = *reinterpret_cast<const v8bf*>(arow + sl);
                v8bf bb = *reinterpret_cast<const v8bf*>(brow + sl);
                D = __builtin_amdgcn_mfma_f32_16x16x32_bf16(a, bb, D, 0, 0, 0);
            }
        }
        // ---- softmax in D-layout: lane holds rows g*4+j, col m=lr
        float2 st[4];
#pragma unroll
        for (int j = 0; j < 4; ++j)
            st[j] = stats[nbase + sub * 64 + w * 16 + g * 4 + j];
#pragma unroll
        for (int j = 0; j < 4; ++j) {
            float lg = (lr < 8) ? (st[j].y * (D[j] - st[j].x * Swm) + cwm) : -1e30f;
            float mx = lg;
            mx = fmaxf(mx, __shfl_xor(mx, 1));
            mx = fmaxf(mx, __shfl_xor(mx, 2));
            mx = fmaxf(mx, __shfl_xor(mx, 4));
            float e = __expf(lg - mx);
            float sme = e;
            sme += __shfl_xor(sme, 1);
            sme += __shfl_xor(sme, 2);
            sme += __shfl_xor(sme, 4);
            float a = e / sme + ATTN_EPS;
            if (lr < 8) {
                at[w * 16 + g * 4 + j][lr] = a * st[j].y;   // a' = a*rstd
                A_acc += a;
                C_acc += a * st[j].y * st[j].x;             // a'*mean
            }
        }
        __syncthreads();   // at visible to all waves
        // ---- z accumulation: thread owns (zm, d-slice ds)
        {
            const __bf16* xcur = &xs[cur][0];
#pragma unroll 4
            for (int n = 0; n < 64; ++n) {
                float av = at[n][zm];
                int r7 = n & 7;
                v8bf x0 = *reinterpret_cast<const v8bf*>(xcur + n * 512 + ((2 * ds)     ^ r7) * 8);
                v8bf x1 = *reinterpret_cast<const v8bf*>(xcur + n * 512 + ((2 * ds + 1) ^ r7) * 8);
#pragma unroll
                for (int i = 0; i < 8; ++i) z[i]     += av * (float)x0[i];
#pragma unroll
                for (int i = 0; i < 8; ++i) z[8 + i] += av * (float)x1[i];
            }
        }
        asm volatile("s_waitcnt vmcnt(0)" ::: "memory");
        __syncthreads();
        cur ^= 1;
    }
#undef STAGE
    // ---- write z_part (coalesced: threads of same zm cover contiguous d)
    {
        float* zp = z_part + (((size_t)(b * 16 + ch) * 8 + zm) * 512 + ds * 16);
#pragma unroll
        for (int c = 0; c < 4; ++c)
            *reinterpret_cast<float4*>(zp + c * 4) =
                make_float4(z[c * 4], z[c * 4 + 1], z[c * 4 + 2], z[c * 4 + 3]);
    }
    // ---- A/cm: reduce over g (shfl 16,32), then over waves (LDS)
    A_acc += __shfl_xor(A_acc, 16); A_acc += __shfl_xor(A_acc, 32);
    C_acc += __shfl_xor(C_acc, 16); C_acc += __shfl_xor(C_acc, 32);
    if (g == 0 && lr < 8) { redA[w][lr] = A_acc; redC[w][lr] = C_acc; }
    __syncthreads();
    if (t < 8) {
        A_part[(b * 16 + ch) * 8 + t]  = redA[0][t] + redA[1][t] + redA[2][t] + redA[3][t];
        cm_part[(b * 16 + ch) * 8 + t] = redC[0][t] + redC[1][t] + redC[2][t] + redC[3][t];
    }
}

// ---------------------------------------------------------------------------
// Kernel 5: finish.  z->updates via Wv, then GRU, LN, MLP -> slots; next q.
// One block per (b,m), 256 threads (tid, half).
// ---------------------------------------------------------------------------
__global__ __launch_bounds__(256) void k_finishq(const float* __restrict__ z_part,
                                                 const float* __restrict__ A_part,
                                                 const float* __restrict__ cm_part,
                                                 const float* __restrict__ slots_in,
                                                 const float* __restrict__ Wv,
                                                 const float* __restrict__ cbv0,
                                                 const float* __restrict__ lnw_in,
                                                 const float* __restrict__ Wih, const float* __restrict__ Whh,
                                                 const float* __restrict__ bih, const float* __restrict__ bhh,
                                                 const float* __restrict__ lnw, const float* __restrict__ lnb,
                                                 const float* __restrict__ W1, const float* __restrict__ b1,
                                                 const float* __restrict__ W2, const float* __restrict__ b2,
                                                 const float* __restrict__ lnsw, const float* __restrict__ lnsb,
                                                 const float* __restrict__ Wq,
                                                 float* __restrict__ slots_out, float* __restrict__ qout) {
    __shared__ float zsh[512];
    __shared__ float us[128], sp[128], hnorm[128], qsrc[128], act[256];
    __shared__ float upart[2][128];
    __shared__ float gpart[2][6][128];
    __shared__ float p2[2][128];
    __shared__ float qpart[2][128];
    __shared__ float red[4];
    __shared__ float A_sh, cm_sh;
    const int t   = threadIdx.x;
    const int tid = t & 127, half = t >> 7;
    const int bm  = blockIdx.x;
    const int b = bm >> 3, m = bm & 7;
    // ---- A, cm reduce over 16 chunks
    if (t < 16) {
        float av = A_part[(b * 16 + t) * 8 + m];
        float cv = cm_part[(b * 16 + t) * 8 + m];
#pragma unroll
        for (int off = 8; off > 0; off >>= 1) { av += __shfl_xor(av, off); cv += __shfl_xor(cv, off); }
        if (t == 0) { A_sh = av; cm_sh = cv; }
    }
    if (half == 0) sp[tid] = slots_in[bm * 128 + tid];
    // ---- z reduce over 16 chunks (thread t covers d=t and d=t+256)
    float z0 = 0.f, z1 = 0.f;
#pragma unroll 4
    for (int ch = 0; ch < 16; ++ch) {
        const float* zp = z_part + ((size_t)(b * 16 + ch) * 8 + m) * 512;
        z0 += zp[t];
        z1 += zp[t + 256];
    }
    __syncthreads();
    zsh[t]       = (z0 - cm_sh) * lnw_in[t];
    zsh[t + 256] = (z1 - cm_sh) * lnw_in[t + 256];
    __syncthreads();
    // ---- updates[s] = (zsh . Wv[s,:]) / A + cbv0[s]   (split-K over halves)
    {
        float acc = 0.f;
        const float* wvp = Wv + (size_t)tid * 512 + half * 256;
        const float* zz  = zsh + half * 256;
#pragma unroll 4
        for (int d = 0; d < 256; d += 4) {
            float4 w = *reinterpret_cast<const float4*>(wvp + d);
            acc += w.x * zz[d] + w.y * zz[d + 1] + w.z * zz[d + 2] + w.w * zz[d + 3];
        }
        upart[half][tid] = acc;
    }
    __syncthreads();
    if (half == 0) us[tid] = (upart[0][tid] + upart[1][tid]) * (1.f / A_sh) + cbv0[tid];
    __syncthreads();
    // ---- GRU partial dots (split-K over halves)
    {
        const int d0g = half * 64;
        float a_r = 0.f, a_z = 0.f, a_n = 0.f, b_r = 0.f, b_z = 0.f, b_n = 0.f;
        const float* Wr = Wih + (size_t)tid * 128 + d0g;
        const float* Wz = Wih + (size_t)(128 + tid) * 128 + d0g;
        const float* Wn = Wih + (size_t)(256 + tid) * 128 + d0g;
        const float* Vr = Whh + (size_t)tid * 128 + d0g;
        const float* Vz = Whh + (size_t)(128 + tid) * 128 + d0g;
        const float* Vn = Whh + (size_t)(256 + tid) * 128 + d0g;
#pragma unroll 4
        for (int d = 0; d < 64; d += 4) {
            float u0 = us[d0g + d], u1 = us[d0g + d + 1], u2 = us[d0g + d + 2], u3 = us[d0g + d + 3];
            float p0 = sp[d0g + d], p1 = sp[d0g + d + 1], p2_ = sp[d0g + d + 2], p3 = sp[d0g + d + 3];
            float4 w;
            w = *reinterpret_cast<const float4*>(Wr + d); a_r += w.x*u0 + w.y*u1 + w.z*u2 + w.w*u3;
            w = *reinterpret_cast<const float4*>(Wz + d); a_z += w.x*u0 + w.y*u1 + w.z*u2 + w.w*u3;
            w = *reinterpret_cast<const float4*>(Wn + d); a_n += w.x*u0 + w.y*u1 + w.z*u2 + w.w*u3;
            w = *reinterpret_cast<const float4*>(Vr + d); b_r += w.x*p0 + w.y*p1 + w.z*p2_ + w.w*p3;
            w = *reinterpret_cast<const float4*>(Vz + d); b_z += w.x*p0 + w.y*p1 + w.z*p2_ + w.w*p3;
            w = *reinterpret_cast<const float4*>(Vn + d); b_n += w.x*p0 + w.y*p1 + w.z*p2_ + w.w*p3;
        }
        gpart[half][0][tid] = a_r; gpart[half][1][tid] = a_z; gpart[half][2][tid] = a_n;
        gpart[half][3][tid] = b_r; gpart[half][4][tid] = b_z; gpart[half][5][tid] = b_n;
    }
    __syncthreads();
    float gir = bih[tid]       + gpart[0][0][tid] + gpart[1][0][tid];
    float giz = bih[128 + tid] + gpart[0][1][tid] + gpart[1][1][tid];
    float gin = bih[256 + tid] + gpart[0][2][tid] + gpart[1][2][tid];
    float ghr = bhh[tid]       + gpart[0][3][tid] + gpart[1][3][tid];
    float ghz = bhh[128 + tid] + gpart[0][4][tid] + gpart[1][4][tid];
    float ghn = bhh[256 + tid] + gpart[0][5][tid] + gpart[1][5][tid];
    float h0 = sp[tid];
    float r  = 1.f / (1.f + __expf(-(gir + ghr)));
    float z  = 1.f / (1.f + __expf(-(giz + ghz)));
    float nn = tanhf(gin + r * ghn);
    float h  = (1.f - z) * nn + z * h0;
    // ---- LN(h)
    if (half == 0) {
        float s = h, s2 = h * h;
#pragma unroll
        for (int off = 32; off > 0; off >>= 1) { s += __shfl_xor(s, off); s2 += __shfl_xor(s2, off); }
        if ((t & 63) == 0) { red[(tid >> 6) * 2] = s; red[(tid >> 6) * 2 + 1] = s2; }
    }
    __syncthreads();
    {
        float S1 = red[0] + red[2], S2 = red[1] + red[3];
        float mean = S1 * (1.f / Ss);
        float rstd = rsqrtf(S2 * (1.f / Ss) - mean * mean + LN_EPS_F);
        if (half == 0) hnorm[tid] = (h - mean) * rstd * lnw[tid] + lnb[tid];
    }
    __syncthreads();
    // ---- MLP1
    {
        float a = b1[t];
        const float* w1r = W1 + (size_t)t * 128;
#pragma unroll 4
        for (int d = 0; d < 128; d += 4) {
            float4 w = *reinterpret_cast<const float4*>(w1r + d);
            a += w.x * hnorm[d] + w.y * hnorm[d + 1] + w.z * hnorm[d + 2] + w.w * hnorm[d + 3];
        }
        act[t] = fmaxf(a, 0.f);
    }
    __syncthreads();
    // ---- MLP2 split-K
    {
        float o = 0.f;
        const int j0 = half * 128;
        const float* w2r = W2 + (size_t)tid * 256 + j0;
#pragma unroll 4
        for (int j = 0; j < 128; j += 4) {
            float4 w = *reinterpret_cast<const float4*>(w2r + j);
            o += w.x * act[j0 + j] + w.y * act[j0 + j + 1] + w.z * act[j0 + j + 2] + w.w * act[j0 + j + 3];
        }
        p2[half][tid] = o;
    }
    __syncthreads();
    float snew = h + b2[tid] + p2[0][tid] + p2[1][tid];
    if (half == 0) slots_out[bm * 128 + tid] = snew;
    // ---- next-iter q
    if (half == 0) {
        float s = snew, s2 = snew * snew;
#pragma unroll
        for (int off = 32; off > 0; off >>= 1) { s += __shfl_xor(s, off); s2 += __shfl_xor(s2, off); }
        if ((t & 63) == 0) { red[(tid >> 6) * 2] = s; red[(tid >> 6) * 2 + 1] = s2; }
    }
    __syncthreads();
    {
        float T1 = red[0] + red[2], T2 = red[1] + red[3];
        float m2 = T1 * (1.f / Ss);
        float rstd2 = rsqrtf(T2 * (1.f / Ss) - m2 * m2 + LN_EPS_F);
        if (half == 0) qsrc[tid] = (snew - m2) * rstd2 * lnsw[tid] + lnsb[tid];
    }
    __syncthreads();
    {
        float qa = 0.f;
        const int d0g = half * 64;
        const float* wr = Wq + (size_t)tid * 128 + d0g;
#pragma unroll 4
        for (int d = 0; d < 64; d += 4) {
            float4 w = *reinterpret_cast<const float4*>(wr + d);
            qa += w.x * qsrc[d0g + d] + w.y * qsrc[d0g + d + 1] + w.z * qsrc[d0g + d + 2] + w.w * qsrc[d0g + d + 3];
        }
        qpart[half][tid] = qa;
    }
    __syncthreads();
    if (half == 0)
        qout[bm * 128 + tid] = (qpart[0][tid] + qpart[1][tid]) * 0.08838834764831845f;
}

// ---------------------------------------------------------------------------
extern "C" void kernel_launch(void* const* d_in, const int* in_sizes, int n_in,
                              void* d_out, int out_size, void* d_ws, size_t ws_size,
                              hipStream_t stream) {
    const float* X          = (const float*)d_in[0];
    const float* slots_init = (const float*)d_in[1];
    const float* ln_in_w    = (const float*)d_in[2];
    const float* ln_in_b    = (const float*)d_in[3];
    const float* ln_slot_w  = (const float*)d_in[4];
    const float* ln_slot_b  = (const float*)d_in[5];
    const float* ln_mlp_w   = (const float*)d_in[6];
    const float* ln_mlp_b   = (const float*)d_in[7];
    const float* Wq         = (const float*)d_in[8];
    const float* Wk         = (const float*)d_in[9];
    const float* Wv         = (const float*)d_in[10];
    const float* gWih       = (const float*)d_in[11];
    const float* gWhh       = (const float*)d_in[12];
    const float* gbih       = (const float*)d_in[13];
    const float* gbhh       = (const float*)d_in[14];
    const float* W1         = (const float*)d_in[15];
    const float* b1         = (const float*)d_in[16];
    const float* W2         = (const float*)d_in[17];
    const float* b2         = (const float*)d_in[18];
    const float* mu         = (const float*)d_in[19];
    const float* lsig       = (const float*)d_in[20];

    char* p = (char*)d_ws;
    float*  cbv0    = (float*)p;  p += 128 * sizeof(float);
    float*  slots   = (float*)p;  p += 32 * 8 * 128 * sizeof(float);               // 128 KB
    float*  qbuf    = (float*)p;  p += 32 * 8 * 128 * sizeof(float);               // 128 KB
    u16*    wlbuf   = (u16*)p;    p += (size_t)32 * 16 * 512 * sizeof(u16);        // 512 KB
    float*  Swb     = (float*)p;  p += 32 * 16 * sizeof(float);
    float*  cwb     = (float*)p;  p += 32 * 16 * sizeof(float);
    float*  A_part  = (float*)p;  p += 32 * 16 * 8 * sizeof(float);                // 16 KB
    float*  cm_part = (float*)p;  p += 32 * 16 * 8 * sizeof(float);                // 16 KB
    float*  z_part  = (float*)p;  p += (size_t)32 * 16 * 8 * 512 * sizeof(float);  // 8.4 MB
    u16*    Xb      = (u16*)p;    p += (size_t)MROWS * Dd * sizeof(u16);           // 134 MB
    float2* stats   = (float2*)p; p += (size_t)MROWS * sizeof(float2);             // 1 MB

    k_cast<<<MROWS / 4, 256, 0, stream>>>(X, Xb, stats);
    k_prep<<<132, 256, 0, stream>>>(Wv, ln_in_b, slots_init, mu, lsig, cbv0, slots);
    k_q<<<256, 128, 0, stream>>>(slots, ln_slot_w, ln_slot_b, Wq, qbuf);

    for (int it = 0; it < 3; ++it) {
        k_wlgen<<<dim3(16, 32), 256, 0, stream>>>(qbuf, Wk, ln_in_w, ln_in_b,
                                                  wlbuf, Swb, cwb);
        k_attnz<<<dim3(16, 32), 256, 0, stream>>>(Xb, stats, wlbuf, Swb, cwb,
                                                  z_part, A_part, cm_part);
        k_finishq<<<256, 256, 0, stream>>>(z_part, A_part, cm_part, slots,
                                           Wv, cbv0, ln_in_w,
                                           gWih, gWhh, gbih, gbhh,
                                           ln_mlp_w, ln_mlp_b, W1, b1, W2, b2,
                                           ln_slot_w, ln_slot_b, Wq,
                                           (it == 2) ? (float*)d_out : slots, qbuf);
    }
}

// Round 7
// 414.645 us; speedup vs baseline: 1.0620x; 1.0620x over previous
//
#include <hip/hip_runtime.h>

typedef __bf16 v8bf __attribute__((ext_vector_type(8)));
typedef __bf16 v4bf __attribute__((ext_vector_type(4)));
typedef float  v4f  __attribute__((ext_vector_type(4)));
typedef unsigned short u16;

#define LN_EPS_F 1e-5f
#define ATTN_EPS 1e-6f

static constexpr int Bsz = 32;
static constexpr int Nn  = 4096;
static constexpr int Dd  = 512;
static constexpr int Ss  = 128;
static constexpr int NSs = 8;
static constexpr int Hh  = 256;
static constexpr int MROWS = Bsz * Nn;   // 131072

__device__ __forceinline__ void load_lds16(const void* g, void* l) {
    __builtin_amdgcn_global_load_lds(
        (const __attribute__((address_space(1))) void*)g,
        (__attribute__((address_space(3))) void*)l, 16, 0, 0);
}

// ---------------------------------------------------------------------------
// Kernel 1: prep — Wkvp = bf16(W*lnw), slots init, cb[n]=lnb·W[n,:],
// Scol[n] = sum_d bf16(W*lnw)[n,d].
// ---------------------------------------------------------------------------
__global__ __launch_bounds__(256) void k_prep(const float* __restrict__ Wk, const float* __restrict__ Wv,
                                              const float* __restrict__ ln_in_w, const float* __restrict__ ln_in_b,
                                              const float* __restrict__ slots_init, const float* __restrict__ mu,
                                              const float* __restrict__ lsig,
                                              u16* __restrict__ Wkvp, float* __restrict__ cb,
                                              float* __restrict__ Scol, float* __restrict__ slots) {
    const int bid = blockIdx.x;
    const int t = threadIdx.x;
    if (bid < 512) {
        int idx = bid * 256 + t;                 // 131072 weight elems
        int n = idx >> 9, d = idx & 511;
        float w = (n < Ss) ? Wk[n * Dd + d] : Wv[(n - Ss) * Dd + d];
        w *= ln_in_w[d];
        __bf16 bv = (__bf16)w;
        Wkvp[idx] = __builtin_bit_cast(u16, bv);
    } else if (bid < 640) {
        int idx = (bid - 512) * 256 + t;         // 32768 slot elems
        int sidx = idx & (Ss - 1);
        slots[idx] = mu[sidx] + expf(lsig[sidx]) * slots_init[idx];
    } else {                                     // bids 640..647: cb + Scol
        const int wid = t >> 6, lane = t & 63;
        const int rowbase = (bid - 640) * 32 + wid * 8;
        const int d0 = lane * 8;
        float4 lw0 = *reinterpret_cast<const float4*>(ln_in_w + d0);
        float4 lw1 = *reinterpret_cast<const float4*>(ln_in_w + d0 + 4);
        float4 lb0 = *reinterpret_cast<const float4*>(ln_in_b + d0);
        float4 lb1 = *reinterpret_cast<const float4*>(ln_in_b + d0 + 4);
        for (int rr = 0; rr < 8; ++rr) {
            int row = rowbase + rr;
            const float* wrow = (row < Ss) ? (Wk + (size_t)row * Dd)
                                           : (Wv + (size_t)(row - Ss) * Dd);
            float4 w0 = *reinterpret_cast<const float4*>(wrow + d0);
            float4 w1 = *reinterpret_cast<const float4*>(wrow + d0 + 4);
            float accb = lb0.x*w0.x + lb0.y*w0.y + lb0.z*w0.z + lb0.w*w0.w
                       + lb1.x*w1.x + lb1.y*w1.y + lb1.z*w1.z + lb1.w*w1.w;
            float accs = (float)(__bf16)(w0.x*lw0.x) + (float)(__bf16)(w0.y*lw0.y)
                       + (float)(__bf16)(w0.z*lw0.z) + (float)(__bf16)(w0.w*lw0.w)
                       + (float)(__bf16)(w1.x*lw1.x) + (float)(__bf16)(w1.y*lw1.y)
                       + (float)(__bf16)(w1.z*lw1.z) + (float)(__bf16)(w1.w*lw1.w);
#pragma unroll
            for (int off = 32; off > 0; off >>= 1) {
                accb += __shfl_xor(accb, off);
                accs += __shfl_xor(accs, off);
            }
            if (lane == 0) { cb[row] = accb; Scol[row] = accs; }
        }
    }
}

// ---------------------------------------------------------------------------
// Kernel 2: fused cast+LN+K/V GEMM.  256x256xBK64, 512 thr / 8 waves.
// A: reg-staged from fp32 X (8 dwordx4/thread/step), stats accumulated in
// regs, fp32->bf16 cvt, XOR-swizzled ds_write into double-buffered As.
// B: global_load_lds double-buffered, source pre-swizzled (as R5, verified).
// Counted vmcnt(12): B(kb+1)[4] + A(kb+1)[8] stay in flight across barrier.
// Epilogue: out = rstd*(acc - mean*Scol) + cb  (affine LN algebra).
// ---------------------------------------------------------------------------
__global__ __launch_bounds__(512) void k_kvgemm(const float* __restrict__ X,
                                                const u16* __restrict__ Wkvp,
                                                const float* __restrict__ cb,
                                                const float* __restrict__ Scol,
                                                u16* __restrict__ kv) {
    __shared__ __bf16 As[2][256 * 64];    // 64 KB
    __shared__ __bf16 Bsh[2][256 * 64];   // 64 KB
    __shared__ float2 stats_sh[256];      // 2 KB
    const int t    = threadIdx.x;
    const int lane = t & 63;
    const int w    = t >> 6;
    const int wr   = w >> 2;              // 0..1: row-half of block tile
    const int wc   = w & 3;               // 0..3: col-quarter
    const int lr   = lane & 15;
    const int g    = lane >> 4;
    const int r7   = lane & 7;
    const size_t m0 = (size_t)blockIdx.x * 256;

    // ---- A staging geometry (reg-stage): thread t owns row ar, 32-col half
    const int ar   = t >> 1;              // 0..255
    const int agr  = (t & 1) * 4;         // granule base (8-elem granules)
    const int ar7  = ar & 7;
    const float* xrow = X + (m0 + ar) * Dd + agr * 8;
    __bf16* adst = &As[0][ar * 64];       // buffer offset added via (buf)*16384

    // ---- B staging geometry (global_load_lds): wave w covers rows w*32..+31
    const int rowoff = lane >> 3;                 // 0..7
    const int swz8   = ((lane & 7) ^ rowoff) * 8; // source elem offset
    const u16* bsrc = Wkvp + (size_t)(w * 32 + rowoff) * Dd + swz8;

    const v4f vzero = {0.f, 0.f, 0.f, 0.f};
    v4f acc[8][4];
#pragma unroll
    for (int i = 0; i < 8; ++i)
#pragma unroll
        for (int j = 0; j < 4; ++j) acc[i][j] = vzero;

    float s1 = 0.f, s2 = 0.f;

#define STAGE_B(buf, kb)                                                        \
    {                                                                           \
        _Pragma("unroll")                                                       \
        for (int i = 0; i < 4; ++i)                                             \
            load_lds16(bsrc + (size_t)i * 8 * Dd + (kb) * 64,                   \
                       &Bsh[buf][(w * 32 + i * 8) * 64]);                       \
    }

    // prologue: A(0) fp32 -> regs, B(0) -> Bs[0]
    float4 a_pre[8];
#pragma unroll
    for (int j = 0; j < 8; ++j)
        a_pre[j] = *reinterpret_cast<const float4*>(xrow + j * 4);
    STAGE_B(0, 0);

#pragma unroll
    for (int kb = 0; kb < 8; ++kb) {
        const int buf = kb & 1;
        // (1) stats + cvt + swizzled ds_write A(kb)
        __bf16* ad = adst + buf * (256 * 64);
#pragma unroll
        for (int g4 = 0; g4 < 4; ++g4) {
            float4 lo = a_pre[g4 * 2];
            float4 hi = a_pre[g4 * 2 + 1];
            s1 += lo.x + lo.y + lo.z + lo.w + hi.x + hi.y + hi.z + hi.w;
            s2 += lo.x*lo.x + lo.y*lo.y + lo.z*lo.z + lo.w*lo.w
                + hi.x*hi.x + hi.y*hi.y + hi.z*hi.z + hi.w*hi.w;
            v8bf o;
            o[0] = (__bf16)lo.x; o[1] = (__bf16)lo.y; o[2] = (__bf16)lo.z; o[3] = (__bf16)lo.w;
            o[4] = (__bf16)hi.x; o[5] = (__bf16)hi.y; o[6] = (__bf16)hi.z; o[7] = (__bf16)hi.w;
            *reinterpret_cast<v8bf*>(ad + ((agr + g4) ^ ar7) * 8) = o;
        }
        // (2) issue A(kb+1) fp32 loads
        if (kb < 7) {
#pragma unroll
            for (int j = 0; j < 8; ++j)
                a_pre[j] = *reinterpret_cast<const float4*>(xrow + (kb + 1) * 64 + j * 4);
        }
        // (3) issue B(kb+1)
        if (kb < 7) STAGE_B(buf ^ 1, kb + 1);
        // (4) B(kb) landed (12 newer: A(kb+1)[8]+B(kb+1)[4]); A writes visible
        if (kb < 7)
            asm volatile("s_waitcnt vmcnt(12) lgkmcnt(0)" ::: "memory");
        else
            asm volatile("s_waitcnt vmcnt(0) lgkmcnt(0)" ::: "memory");
        __builtin_amdgcn_s_barrier();
        // (5) MFMA on As[buf], Bs[buf]
#pragma unroll
        for (int ks = 0; ks < 2; ++ks) {
            const int co = ((ks * 4 + g) ^ r7) * 8;   // swizzled 16B slot
            v8bf a[8], b[4];
#pragma unroll
            for (int mi = 0; mi < 8; ++mi)
                a[mi] = *reinterpret_cast<const v8bf*>(
                    &As[buf][(wr * 128 + mi * 16 + lr) * 64 + co]);
#pragma unroll
            for (int ni = 0; ni < 4; ++ni)
                b[ni] = *reinterpret_cast<const v8bf*>(
                    &Bsh[buf][(wc * 64 + ni * 16 + lr) * 64 + co]);
#pragma unroll
            for (int ni = 0; ni < 4; ++ni)
#pragma unroll
                for (int mi = 0; mi < 8; ++mi)
                    acc[mi][ni] = __builtin_amdgcn_mfma_f32_16x16x32_bf16(a[mi], b[ni], acc[mi][ni], 0, 0, 0);
        }
        // (6) protect buffers before next iter's writes
        __builtin_amdgcn_s_barrier();
    }
#undef STAGE_B
    // ---- stats: pair (2r, 2r+1) holds the two halves of row r
    s1 += __shfl_xor(s1, 1);
    s2 += __shfl_xor(s2, 1);
    if ((t & 1) == 0) {
        float m = s1 * (1.f / Dd);
        float v = s2 * (1.f / Dd) - m * m;
        stats_sh[ar] = make_float2(m, rsqrtf(v + LN_EPS_F));
    }
    __syncthreads();
    // ---- epilogue: out = rstd*(acc - m*Scol) + cb
    float Sn[4], cbv[4];
#pragma unroll
    for (int ni = 0; ni < 4; ++ni) {
        int col = wc * 64 + ni * 16 + lr;
        Sn[ni]  = Scol[col];
        cbv[ni] = cb[col];
    }
#pragma unroll
    for (int mi = 0; mi < 8; ++mi)
#pragma unroll
        for (int j = 0; j < 4; ++j) {
            int rl = wr * 128 + mi * 16 + g * 4 + j;
            float2 st = stats_sh[rl];
            size_t mg = m0 + rl;
#pragma unroll
            for (int ni = 0; ni < 4; ++ni) {
                int col = wc * 64 + ni * 16 + lr;
                float val = st.y * (acc[mi][ni][j] - st.x * Sn[ni]) + cbv[ni];
                __bf16 bv = (__bf16)val;
                kv[mg * 256 + col] = __builtin_bit_cast(u16, bv);
            }
        }
}

// ---------------------------------------------------------------------------
// Kernel 3: initial q = LN_slot(slots) @ Wq^T * scale.  One block per (b,m).
// ---------------------------------------------------------------------------
__global__ __launch_bounds__(128) void k_q(const float* __restrict__ slots,
                                           const float* __restrict__ lnw, const float* __restrict__ lnb,
                                           const float* __restrict__ Wq, float* __restrict__ q) {
    __shared__ float xs[128];
    __shared__ float red[4];
    const int t = threadIdx.x;
    const int bm = blockIdx.x;
    float x = slots[bm * 128 + t];
    float s = x, s2 = x * x;
#pragma unroll
    for (int off = 32; off > 0; off >>= 1) { s += __shfl_xor(s, off); s2 += __shfl_xor(s2, off); }
    const int wid = t >> 6, lane = t & 63;
    if (lane == 0) { red[wid * 2] = s; red[wid * 2 + 1] = s2; }
    __syncthreads();
    float S1 = red[0] + red[2], S2 = red[1] + red[3];
    float m = S1 * (1.f / 128.f);
    float rstd = rsqrtf(S2 * (1.f / 128.f) - m * m + LN_EPS_F);
    xs[t] = (x - m) * rstd * lnw[t] + lnb[t];
    __syncthreads();
    const float* wr = Wq + (size_t)t * 128;
    float acc = 0.f;
#pragma unroll 8
    for (int d = 0; d < 128; d += 4) {
        float4 w = *reinterpret_cast<const float4*>(wr + d);
        acc += w.x * xs[d] + w.y * xs[d + 1] + w.z * xs[d + 2] + w.w * xs[d + 3];
    }
    q[bm * 128 + t] = acc * 0.08838834764831845f;
}

// ---------------------------------------------------------------------------
// Kernel 4: fused attn logits + softmax + partial updates per (b,chunk).
// ---------------------------------------------------------------------------
__global__ __launch_bounds__(256) void k_attnupd(const u16* __restrict__ kv, const float* __restrict__ q,
                                                 float* __restrict__ upd_part, float* __restrict__ colsum_part) {
    __shared__ float qs[8 * 128];
    __shared__ float at[128][8];
    __shared__ __bf16 vt[128][128];
    __shared__ float colpart[4][8];
    const int b  = blockIdx.y;
    const int ch = blockIdx.x;
    const int t  = threadIdx.x;
    const int lane = t & 63, wv = t >> 6;
    *reinterpret_cast<float4*>(&qs[t * 4]) = *reinterpret_cast<const float4*>(&q[b * 1024 + t * 4]);
    __syncthreads();
    {
        const int rsub = lane >> 4;
        const int csub = (lane & 15) * 8;
#pragma unroll
        for (int p = 0; p < 8; ++p) {
            int row = wv * 32 + p * 4;
            const u16* src = kv + ((size_t)(b * Nn + ch * 128 + row + rsub)) * 256 + 128 + csub;
            load_lds16(src, &vt[row][0]);
        }
    }
    const int nl   = t >> 1;
    const int half = t & 1;
    const u16* krow = kv + ((size_t)(b * Nn + ch * 128 + nl)) * 256 + half * 64;
    float acc[8] = {0.f, 0.f, 0.f, 0.f, 0.f, 0.f, 0.f, 0.f};
#pragma unroll
    for (int c = 0; c < 8; ++c) {
        v8bf kvv = *reinterpret_cast<const v8bf*>(krow + c * 8);
        float kf[8];
#pragma unroll
        for (int j = 0; j < 8; ++j) kf[j] = (float)kvv[j];
#pragma unroll
        for (int m = 0; m < 8; ++m) {
            const float* qrow = &qs[m * 128 + half * 64 + c * 8];
            float aa = 0.f;
#pragma unroll
            for (int j = 0; j < 8; ++j) aa += kf[j] * qrow[j];
            acc[m] += aa;
        }
    }
#pragma unroll
    for (int m = 0; m < 8; ++m) acc[m] += __shfl_xor(acc[m], 1);
    float mx = acc[0];
#pragma unroll
    for (int m = 1; m < 8; ++m) mx = fmaxf(mx, acc[m]);
    float e[8]; float ssum = 0.f;
#pragma unroll
    for (int m = 0; m < 8; ++m) { e[m] = __expf(acc[m] - mx); ssum += e[m]; }
    float inv = 1.0f / ssum;
    float a8[8];
#pragma unroll
    for (int m = 0; m < 8; ++m) a8[m] = e[m] * inv + ATTN_EPS;
    *reinterpret_cast<float4*>(&at[nl][half * 4]) =
        make_float4(a8[half * 4], a8[half * 4 + 1], a8[half * 4 + 2], a8[half * 4 + 3]);
#pragma unroll
    for (int m = 0; m < 8; ++m) {
        float v = a8[m];
#pragma unroll
        for (int off = 32; off > 0; off >>= 1) v += __shfl_xor(v, off);
        if (lane == 0) colpart[wv][m] = v * 0.5f;
    }
    __syncthreads();
    const int m2 = t >> 5;
    const int s0 = (t & 31) * 4;
    float a0 = 0.f, a1 = 0.f, a2 = 0.f, a3 = 0.f;
#pragma unroll 4
    for (int n = 0; n < 128; ++n) {
        float a = at[n][m2];
        v4bf vvv = *reinterpret_cast<const v4bf*>(&vt[n][s0]);
        a0 += a * (float)vvv[0];
        a1 += a * (float)vvv[1];
        a2 += a * (float)vvv[2];
        a3 += a * (float)vvv[3];
    }
    *reinterpret_cast<float4*>(upd_part + ((size_t)(b * 32 + ch) * 8 + m2) * 128 + s0) =
        make_float4(a0, a1, a2, a3);
    if (t < 8)
        colsum_part[(b * 32 + ch) * 8 + t] =
            colpart[0][t] + colpart[1][t] + colpart[2][t] + colpart[3][t];
}

// ---------------------------------------------------------------------------
// Kernel 5: reduce partials, GRU, LN, MLP -> new slots; next-iter q.
// 256 threads: (tid, half) split-K halves the serial fma chains; 4 waves.
// ---------------------------------------------------------------------------
__global__ __launch_bounds__(256) void k_finishq(const float* __restrict__ upd_part,
                                                 const float* __restrict__ colsum_part,
                                                 const float* __restrict__ slots_in,
                                                 const float* __restrict__ Wih, const float* __restrict__ Whh,
                                                 const float* __restrict__ bih, const float* __restrict__ bhh,
                                                 const float* __restrict__ lnw, const float* __restrict__ lnb,
                                                 const float* __restrict__ W1, const float* __restrict__ b1,
                                                 const float* __restrict__ W2, const float* __restrict__ b2,
                                                 const float* __restrict__ lnsw, const float* __restrict__ lnsb,
                                                 const float* __restrict__ Wq,
                                                 float* __restrict__ slots_out, float* __restrict__ qout) {
    __shared__ float us[128], sp[128], hnorm[128], qsrc[128], act[256];
    __shared__ float upart[2][128];
    __shared__ float gpart[2][6][128];
    __shared__ float p2[2][128];
    __shared__ float qpart[2][128];
    __shared__ float red[4];
    __shared__ float csum_sh;
    const int t   = threadIdx.x;
    const int tid = t & 127, half = t >> 7;
    const int bm  = blockIdx.x;
    const int b = bm >> 3, m = bm & 7;
    if (t < 64) {
        float v = (t < 32) ? colsum_part[(b * 32 + t) * 8 + m] : 0.f;
#pragma unroll
        for (int off = 32; off > 0; off >>= 1) v += __shfl_xor(v, off);
        if (t == 0) csum_sh = v;
    }
    float u = 0.f;
#pragma unroll 4
    for (int chk = half * 16; chk < half * 16 + 16; ++chk)
        u += upd_part[((size_t)(b * 32 + chk) * 8 + m) * 128 + tid];
    upart[half][tid] = u;
    if (half == 0) sp[tid] = slots_in[bm * 128 + tid];
    __syncthreads();
    if (half == 0) us[tid] = (upart[0][tid] + upart[1][tid]) * (1.f / csum_sh);
    __syncthreads();
    // ---- GRU partial dots (split-K over halves)
    {
        const int d0g = half * 64;
        float a_r = 0.f, a_z = 0.f, a_n = 0.f, b_r = 0.f, b_z = 0.f, b_n = 0.f;
        const float* Wr = Wih + (size_t)tid * 128 + d0g;
        const float* Wz = Wih + (size_t)(128 + tid) * 128 + d0g;
        const float* Wn = Wih + (size_t)(256 + tid) * 128 + d0g;
        const float* Vr = Whh + (size_t)tid * 128 + d0g;
        const float* Vz = Whh + (size_t)(128 + tid) * 128 + d0g;
        const float* Vn = Whh + (size_t)(256 + tid) * 128 + d0g;
#pragma unroll 4
        for (int d = 0; d < 64; d += 4) {
            float u0 = us[d0g + d], u1 = us[d0g + d + 1], u2 = us[d0g + d + 2], u3 = us[d0g + d + 3];
            float p0 = sp[d0g + d], p1 = sp[d0g + d + 1], p2_ = sp[d0g + d + 2], p3 = sp[d0g + d + 3];
            float4 w;
            w = *reinterpret_cast<const float4*>(Wr + d); a_r += w.x*u0 + w.y*u1 + w.z*u2 + w.w*u3;
            w = *reinterpret_cast<const float4*>(Wz + d); a_z += w.x*u0 + w.y*u1 + w.z*u2 + w.w*u3;
            w = *reinterpret_cast<const float4*>(Wn + d); a_n += w.x*u0 + w.y*u1 + w.z*u2 + w.w*u3;
            w = *reinterpret_cast<const float4*>(Vr + d); b_r += w.x*p0 + w.y*p1 + w.z*p2_ + w.w*p3;
            w = *reinterpret_cast<const float4*>(Vz + d); b_z += w.x*p0 + w.y*p1 + w.z*p2_ + w.w*p3;
            w = *reinterpret_cast<const float4*>(Vn + d); b_n += w.x*p0 + w.y*p1 + w.z*p2_ + w.w*p3;
        }
        gpart[half][0][tid] = a_r; gpart[half][1][tid] = a_z; gpart[half][2][tid] = a_n;
        gpart[half][3][tid] = b_r; gpart[half][4][tid] = b_z; gpart[half][5][tid] = b_n;
    }
    __syncthreads();
    float gir = bih[tid]       + gpart[0][0][tid] + gpart[1][0][tid];
    float giz = bih[128 + tid] + gpart[0][1][tid] + gpart[1][1][tid];
    float gin = bih[256 + tid] + gpart[0][2][tid] + gpart[1][2][tid];
    float ghr = bhh[tid]       + gpart[0][3][tid] + gpart[1][3][tid];
    float ghz = bhh[128 + tid] + gpart[0][4][tid] + gpart[1][4][tid];
    float ghn = bhh[256 + tid] + gpart[0][5][tid] + gpart[1][5][tid];
    float h0 = sp[tid];
    float r  = 1.f / (1.f + __expf(-(gir + ghr)));
    float z  = 1.f / (1.f + __expf(-(giz + ghz)));
    float nn = tanhf(gin + r * ghn);
    float h  = (1.f - z) * nn + z * h0;
    // ---- LN(h)
    if (half == 0) {
        float s = h, s2 = h * h;
#pragma unroll
        for (int off = 32; off > 0; off >>= 1) { s += __shfl_xor(s, off); s2 += __shfl_xor(s2, off); }
        if ((t & 63) == 0) { red[(tid >> 6) * 2] = s; red[(tid >> 6) * 2 + 1] = s2; }
    }
    __syncthreads();
    {
        float S1 = red[0] + red[2], S2 = red[1] + red[3];
        float mean = S1 * (1.f / Ss);
        float rstd = rsqrtf(S2 * (1.f / Ss) - mean * mean + LN_EPS_F);
        if (half == 0) hnorm[tid] = (h - mean) * rstd * lnw[tid] + lnb[tid];
    }
    __syncthreads();
    // ---- MLP1
    {
        float a = b1[t];
        const float* w1r = W1 + (size_t)t * 128;
#pragma unroll 4
        for (int d = 0; d < 128; d += 4) {
            float4 w = *reinterpret_cast<const float4*>(w1r + d);
            a += w.x * hnorm[d] + w.y * hnorm[d + 1] + w.z * hnorm[d + 2] + w.w * hnorm[d + 3];
        }
        act[t] = fmaxf(a, 0.f);
    }
    __syncthreads();
    // ---- MLP2 split-K
    {
        float o = 0.f;
        const int j0 = half * 128;
        const float* w2r = W2 + (size_t)tid * 256 + j0;
#pragma unroll 4
        for (int j = 0; j < 128; j += 4) {
            float4 w = *reinterpret_cast<const float4*>(w2r + j);
            o += w.x * act[j0 + j] + w.y * act[j0 + j + 1] + w.z * act[j0 + j + 2] + w.w * act[j0 + j + 3];
        }
        p2[half][tid] = o;
    }
    __syncthreads();
    float snew = h + b2[tid] + p2[0][tid] + p2[1][tid];
    if (half == 0) slots_out[bm * 128 + tid] = snew;
    // ---- next-iter q
    if (half == 0) {
        float s = snew, s2 = snew * snew;
#pragma unroll
        for (int off = 32; off > 0; off >>= 1) { s += __shfl_xor(s, off); s2 += __shfl_xor(s2, off); }
        if ((t & 63) == 0) { red[(tid >> 6) * 2] = s; red[(tid >> 6) * 2 + 1] = s2; }
    }
    __syncthreads();
    {
        float T1 = red[0] + red[2], T2 = red[1] + red[3];
        float m2 = T1 * (1.f / Ss);
        float rstd2 = rsqrtf(T2 * (1.f / Ss) - m2 * m2 + LN_EPS_F);
        if (half == 0) qsrc[tid] = (snew - m2) * rstd2 * lnsw[tid] + lnsb[tid];
    }
    __syncthreads();
    {
        float qa = 0.f;
        const int d0g = half * 64;
        const float* wr = Wq + (size_t)tid * 128 + d0g;
#pragma unroll 4
        for (int d = 0; d < 64; d += 4) {
            float4 w = *reinterpret_cast<const float4*>(wr + d);
            qa += w.x * qsrc[d0g + d] + w.y * qsrc[d0g + d + 1] + w.z * qsrc[d0g + d + 2] + w.w * qsrc[d0g + d + 3];
        }
        qpart[half][tid] = qa;
    }
    __syncthreads();
    if (half == 0)
        qout[bm * 128 + tid] = (qpart[0][tid] + qpart[1][tid]) * 0.08838834764831845f;
}

// ---------------------------------------------------------------------------
extern "C" void kernel_launch(void* const* d_in, const int* in_sizes, int n_in,
                              void* d_out, int out_size, void* d_ws, size_t ws_size,
                              hipStream_t stream) {
    const float* X          = (const float*)d_in[0];
    const float* slots_init = (const float*)d_in[1];
    const float* ln_in_w    = (const float*)d_in[2];
    const float* ln_in_b    = (const float*)d_in[3];
    const float* ln_slot_w  = (const float*)d_in[4];
    const float* ln_slot_b  = (const float*)d_in[5];
    const float* ln_mlp_w   = (const float*)d_in[6];
    const float* ln_mlp_b   = (const float*)d_in[7];
    const float* Wq         = (const float*)d_in[8];
    const float* Wk         = (const float*)d_in[9];
    const float* Wv         = (const float*)d_in[10];
    const float* gWih       = (const float*)d_in[11];
    const float* gWhh       = (const float*)d_in[12];
    const float* gbih       = (const float*)d_in[13];
    const float* gbhh       = (const float*)d_in[14];
    const float* W1         = (const float*)d_in[15];
    const float* b1         = (const float*)d_in[16];
    const float* W2         = (const float*)d_in[17];
    const float* b2         = (const float*)d_in[18];
    const float* mu         = (const float*)d_in[19];
    const float* lsig       = (const float*)d_in[20];

    char* p = (char*)d_ws;
    u16*    Wkvp        = (u16*)p;    p += (size_t)256 * 512 * sizeof(u16);           // 256 KB
    float*  cb          = (float*)p;  p += 256 * sizeof(float);
    float*  Scol        = (float*)p;  p += 256 * sizeof(float);
    float*  slots       = (float*)p;  p += 32 * 8 * 128 * sizeof(float);              // 128 KB
    float*  qbuf        = (float*)p;  p += 32 * 8 * 128 * sizeof(float);              // 128 KB
    float*  colsum_part = (float*)p;  p += 32 * 32 * 8 * sizeof(float);               // 32 KB
    float*  upd_part    = (float*)p;  p += (size_t)32 * 32 * 8 * 128 * sizeof(float); // 4 MB
    u16*    kv          = (u16*)p;    p += (size_t)MROWS * 256 * sizeof(u16);         // 67 MB

    k_prep<<<648, 256, 0, stream>>>(Wk, Wv, ln_in_w, ln_in_b, slots_init, mu, lsig,
                                    Wkvp, cb, Scol, slots);
    k_kvgemm<<<MROWS / 256, 512, 0, stream>>>(X, Wkvp, cb, Scol, kv);
    k_q<<<256, 128, 0, stream>>>(slots, ln_slot_w, ln_slot_b, Wq, qbuf);

    for (int it = 0; it < 3; ++it) {
        k_attnupd<<<dim3(32, 32), 256, 0, stream>>>(kv, qbuf, upd_part, colsum_part);
        k_finishq<<<256, 256, 0, stream>>>(upd_part, colsum_part, slots,
                                           gWih, gWhh, gbih, gbhh,
                                           ln_mlp_w, ln_mlp_b, W1, b1, W2, b2,
                                           ln_slot_w, ln_slot_b, Wq,
                                           (it == 2) ? (float*)d_out : slots, qbuf);
    }
}

// Round 8
// 322.083 us; speedup vs baseline: 1.3671x; 1.2874x over previous
//
#include <hip/hip_runtime.h>

typedef __bf16 v8bf __attribute__((ext_vector_type(8)));
typedef __bf16 v4bf __attribute__((ext_vector_type(4)));
typedef float  v4f  __attribute__((ext_vector_type(4)));
typedef unsigned short u16;

#define LN_EPS_F 1e-5f
#define ATTN_EPS 1e-6f

static constexpr int Bsz = 32;
static constexpr int Nn  = 4096;
static constexpr int Dd  = 512;
static constexpr int Ss  = 128;
static constexpr int NSs = 8;
static constexpr int Hh  = 256;
static constexpr int MROWS = Bsz * Nn;   // 131072

__device__ __forceinline__ void load_lds16(const void* g, void* l) {
    __builtin_amdgcn_global_load_lds(
        (const __attribute__((address_space(1))) void*)g,
        (__attribute__((address_space(3))) void*)l, 16, 0, 0);
}

// ---------------------------------------------------------------------------
// Kernel 0: streaming cast X fp32 -> bf16 + per-row LN stats (mean, rstd).
// ---------------------------------------------------------------------------
__global__ __launch_bounds__(256) void k_cast(const float* __restrict__ X,
                                              u16* __restrict__ Xb,
                                              float2* __restrict__ stats) {
    const int wid = threadIdx.x >> 6, lane = threadIdx.x & 63;
    const int row = blockIdx.x * 4 + wid;
    const float4* xp = reinterpret_cast<const float4*>(X + (size_t)row * Dd) + lane * 2;
    float4 a = xp[0];
    float4 b = xp[1];
    float s  = a.x + a.y + a.z + a.w + b.x + b.y + b.z + b.w;
    float s2 = a.x*a.x + a.y*a.y + a.z*a.z + a.w*a.w
             + b.x*b.x + b.y*b.y + b.z*b.z + b.w*b.w;
    v8bf o;
    o[0] = (__bf16)a.x; o[1] = (__bf16)a.y; o[2] = (__bf16)a.z; o[3] = (__bf16)a.w;
    o[4] = (__bf16)b.x; o[5] = (__bf16)b.y; o[6] = (__bf16)b.z; o[7] = (__bf16)b.w;
    *reinterpret_cast<v8bf*>(Xb + (size_t)row * Dd + lane * 8) = o;
#pragma unroll
    for (int off = 32; off > 0; off >>= 1) {
        s  += __shfl_xor(s, off);
        s2 += __shfl_xor(s2, off);
    }
    if (lane == 0) {
        float m = s * (1.0f / Dd);
        float v = s2 * (1.0f / Dd) - m * m;
        stats[row] = make_float2(m, rsqrtf(v + LN_EPS_F));
    }
}

// ---------------------------------------------------------------------------
// Kernel 1: prep — Wkvp = bf16(W*lnw), slots init, cb[n]=lnb·W[n,:],
// Scol[n] = sum_d bf16(W*lnw)[n,d].
// ---------------------------------------------------------------------------
__global__ __launch_bounds__(256) void k_prep(const float* __restrict__ Wk, const float* __restrict__ Wv,
                                              const float* __restrict__ ln_in_w, const float* __restrict__ ln_in_b,
                                              const float* __restrict__ slots_init, const float* __restrict__ mu,
                                              const float* __restrict__ lsig,
                                              u16* __restrict__ Wkvp, float* __restrict__ cb,
                                              float* __restrict__ Scol, float* __restrict__ slots) {
    const int bid = blockIdx.x;
    const int t = threadIdx.x;
    if (bid < 512) {
        int idx = bid * 256 + t;                 // 131072 weight elems
        int n = idx >> 9, d = idx & 511;
        float w = (n < Ss) ? Wk[n * Dd + d] : Wv[(n - Ss) * Dd + d];
        w *= ln_in_w[d];
        __bf16 bv = (__bf16)w;
        Wkvp[idx] = __builtin_bit_cast(u16, bv);
    } else if (bid < 640) {
        int idx = (bid - 512) * 256 + t;         // 32768 slot elems
        int sidx = idx & (Ss - 1);
        slots[idx] = mu[sidx] + expf(lsig[sidx]) * slots_init[idx];
    } else {                                     // bids 640..647: cb + Scol
        const int wid = t >> 6, lane = t & 63;
        const int rowbase = (bid - 640) * 32 + wid * 8;
        const int d0 = lane * 8;
        float4 lw0 = *reinterpret_cast<const float4*>(ln_in_w + d0);
        float4 lw1 = *reinterpret_cast<const float4*>(ln_in_w + d0 + 4);
        float4 lb0 = *reinterpret_cast<const float4*>(ln_in_b + d0);
        float4 lb1 = *reinterpret_cast<const float4*>(ln_in_b + d0 + 4);
        for (int rr = 0; rr < 8; ++rr) {
            int row = rowbase + rr;
            const float* wrow = (row < Ss) ? (Wk + (size_t)row * Dd)
                                           : (Wv + (size_t)(row - Ss) * Dd);
            float4 w0 = *reinterpret_cast<const float4*>(wrow + d0);
            float4 w1 = *reinterpret_cast<const float4*>(wrow + d0 + 4);
            float accb = lb0.x*w0.x + lb0.y*w0.y + lb0.z*w0.z + lb0.w*w0.w
                       + lb1.x*w1.x + lb1.y*w1.y + lb1.z*w1.z + lb1.w*w1.w;
            float accs = (float)(__bf16)(w0.x*lw0.x) + (float)(__bf16)(w0.y*lw0.y)
                       + (float)(__bf16)(w0.z*lw0.z) + (float)(__bf16)(w0.w*lw0.w)
                       + (float)(__bf16)(w1.x*lw1.x) + (float)(__bf16)(w1.y*lw1.y)
                       + (float)(__bf16)(w1.z*lw1.z) + (float)(__bf16)(w1.w*lw1.w);
#pragma unroll
            for (int off = 32; off > 0; off >>= 1) {
                accb += __shfl_xor(accb, off);
                accs += __shfl_xor(accs, off);
            }
            if (lane == 0) { cb[row] = accb; Scol[row] = accs; }
        }
    }
}

// ---------------------------------------------------------------------------
// Kernel 2: K/V GEMM, 128x128xBK32 tile, 256 thr / 4 waves (wave 64x64).
// LDS 33 KB + launch_bounds(256,3) -> 3-4 blocks/CU (the R5-R7 versions were
// locked at 1 block/CU; independent blocks hide the staging stalls, m114).
// A,B via global_load_lds, dbuf, counted vmcnt(4).  Swizzle for 64B rows:
// phys slot = g ^ ((row>>1)&3)  (8 bank-quads x 2 lanes = conflict-free),
// source pre-swizzled (rule 21).  Grid (1024,2): both N-halves of an A-tile
// land on the same XCD (linear ids differ by 1024 = 0 mod 8).
// Epilogue: out = rstd*(acc - mean*Scol) + cb  (LN algebra, stats from cast).
// ---------------------------------------------------------------------------
__global__ __launch_bounds__(256, 3) void k_kvgemm(const u16* __restrict__ Xb,
                                                   const float2* __restrict__ stats,
                                                   const u16* __restrict__ Wkvp,
                                                   const float* __restrict__ cb,
                                                   const float* __restrict__ Scol,
                                                   u16* __restrict__ kv) {
    __shared__ __bf16 As[2][128 * 32];    // 16 KB
    __shared__ __bf16 Bsh[2][128 * 32];   // 16 KB
    __shared__ float2 stats_sh[128];      // 1 KB
    const int t    = threadIdx.x;
    const int lane = t & 63;
    const int w    = t >> 6;              // 0..3
    const int wr   = w >> 1;              // row-half of 128
    const int wc   = w & 1;               // col-half of 128
    const int lr   = lane & 15;
    const int g    = lane >> 4;           // 0..3
    const size_t m0 = (size_t)blockIdx.x * 128;
    const int n0   = blockIdx.y * 128;

    // staging: instr covers 16 rows x 64B; lane l -> row l>>2, slot l&3.
    // source elem offset = (slot ^ ((row>>1)&3)) * 8  (inverse of read swz)
    const int r16  = lane >> 2;                               // 0..15
    const int swze = ((lane & 3) ^ ((r16 >> 1) & 3)) * 8;
    const u16* asrc = Xb   + (m0 + w * 32 + r16) * 512 + swze;
    const u16* bsrc = Wkvp + (size_t)(n0 + w * 32 + r16) * 512 + swze;

    if (t < 128) stats_sh[t] = stats[m0 + t];

    const v4f vzero = {0.f, 0.f, 0.f, 0.f};
    v4f acc[4][4];
#pragma unroll
    for (int i = 0; i < 4; ++i)
#pragma unroll
        for (int j = 0; j < 4; ++j) acc[i][j] = vzero;

#define STAGE(buf, kb)                                                          \
    {                                                                           \
        _Pragma("unroll")                                                       \
        for (int i = 0; i < 2; ++i) {                                           \
            load_lds16(asrc + (size_t)i * 16 * 512 + (kb) * 32,                 \
                       &As[buf][(w * 32 + i * 16) * 32]);                       \
            load_lds16(bsrc + (size_t)i * 16 * 512 + (kb) * 32,                 \
                       &Bsh[buf][(w * 32 + i * 16) * 32]);                      \
        }                                                                       \
    }

    STAGE(0, 0);

    const int co = (g ^ ((lr >> 1) & 3)) * 8;   // swizzled read slot (all mi/ni)
#pragma unroll
    for (int kb = 0; kb < 16; ++kb) {
        const int buf = kb & 1;
        if (kb < 15) STAGE(buf ^ 1, kb + 1);
        if (kb < 15)
            asm volatile("s_waitcnt vmcnt(4)" ::: "memory");
        else
            asm volatile("s_waitcnt vmcnt(0)" ::: "memory");
        __builtin_amdgcn_s_barrier();
        v8bf a[4], b[4];
#pragma unroll
        for (int mi = 0; mi < 4; ++mi)
            a[mi] = *reinterpret_cast<const v8bf*>(
                &As[buf][(wr * 64 + mi * 16 + lr) * 32 + co]);
#pragma unroll
        for (int ni = 0; ni < 4; ++ni)
            b[ni] = *reinterpret_cast<const v8bf*>(
                &Bsh[buf][(wc * 64 + ni * 16 + lr) * 32 + co]);
#pragma unroll
        for (int ni = 0; ni < 4; ++ni)
#pragma unroll
            for (int mi = 0; mi < 4; ++mi)
                acc[mi][ni] = __builtin_amdgcn_mfma_f32_16x16x32_bf16(a[mi], b[ni], acc[mi][ni], 0, 0, 0);
        __builtin_amdgcn_s_barrier();
    }
#undef STAGE
    // ---- epilogue: out = rstd*(acc - m*Scol) + cb
    float Sn[4], cbv[4];
#pragma unroll
    for (int ni = 0; ni < 4; ++ni) {
        int col = n0 + wc * 64 + ni * 16 + lr;
        Sn[ni]  = Scol[col];
        cbv[ni] = cb[col];
    }
#pragma unroll
    for (int mi = 0; mi < 4; ++mi)
#pragma unroll
        for (int j = 0; j < 4; ++j) {
            int rl = wr * 64 + mi * 16 + g * 4 + j;
            float2 st = stats_sh[rl];
            size_t mg = m0 + rl;
#pragma unroll
            for (int ni = 0; ni < 4; ++ni) {
                int col = n0 + wc * 64 + ni * 16 + lr;
                float val = st.y * (acc[mi][ni][j] - st.x * Sn[ni]) + cbv[ni];
                __bf16 bv = (__bf16)val;
                kv[mg * 256 + col] = __builtin_bit_cast(u16, bv);
            }
        }
}

// ---------------------------------------------------------------------------
// Kernel 3: initial q = LN_slot(slots) @ Wq^T * scale.  One block per (b,m).
// ---------------------------------------------------------------------------
__global__ __launch_bounds__(128) void k_q(const float* __restrict__ slots,
                                           const float* __restrict__ lnw, const float* __restrict__ lnb,
                                           const float* __restrict__ Wq, float* __restrict__ q) {
    __shared__ float xs[128];
    __shared__ float red[4];
    const int t = threadIdx.x;
    const int bm = blockIdx.x;
    float x = slots[bm * 128 + t];
    float s = x, s2 = x * x;
#pragma unroll
    for (int off = 32; off > 0; off >>= 1) { s += __shfl_xor(s, off); s2 += __shfl_xor(s2, off); }
    const int wid = t >> 6, lane = t & 63;
    if (lane == 0) { red[wid * 2] = s; red[wid * 2 + 1] = s2; }
    __syncthreads();
    float S1 = red[0] + red[2], S2 = red[1] + red[3];
    float m = S1 * (1.f / 128.f);
    float rstd = rsqrtf(S2 * (1.f / 128.f) - m * m + LN_EPS_F);
    xs[t] = (x - m) * rstd * lnw[t] + lnb[t];
    __syncthreads();
    const float* wr = Wq + (size_t)t * 128;
    float acc = 0.f;
#pragma unroll 8
    for (int d = 0; d < 128; d += 4) {
        float4 w = *reinterpret_cast<const float4*>(wr + d);
        acc += w.x * xs[d] + w.y * xs[d + 1] + w.z * xs[d + 2] + w.w * xs[d + 3];
    }
    q[bm * 128 + t] = acc * 0.08838834764831845f;
}

// ---------------------------------------------------------------------------
// Kernel 4: fused attn logits + softmax + partial updates per (b,chunk).
// ---------------------------------------------------------------------------
__global__ __launch_bounds__(256) void k_attnupd(const u16* __restrict__ kv, const float* __restrict__ q,
                                                 float* __restrict__ upd_part, float* __restrict__ colsum_part) {
    __shared__ float qs[8 * 128];
    __shared__ float at[128][8];
    __shared__ __bf16 vt[128][128];
    __shared__ float colpart[4][8];
    const int b  = blockIdx.y;
    const int ch = blockIdx.x;
    const int t  = threadIdx.x;
    const int lane = t & 63, wv = t >> 6;
    *reinterpret_cast<float4*>(&qs[t * 4]) = *reinterpret_cast<const float4*>(&q[b * 1024 + t * 4]);
    __syncthreads();
    {
        const int rsub = lane >> 4;
        const int csub = (lane & 15) * 8;
#pragma unroll
        for (int p = 0; p < 8; ++p) {
            int row = wv * 32 + p * 4;
            const u16* src = kv + ((size_t)(b * Nn + ch * 128 + row + rsub)) * 256 + 128 + csub;
            load_lds16(src, &vt[row][0]);
        }
    }
    const int nl   = t >> 1;
    const int half = t & 1;
    const u16* krow = kv + ((size_t)(b * Nn + ch * 128 + nl)) * 256 + half * 64;
    float acc[8] = {0.f, 0.f, 0.f, 0.f, 0.f, 0.f, 0.f, 0.f};
#pragma unroll
    for (int c = 0; c < 8; ++c) {
        v8bf kvv = *reinterpret_cast<const v8bf*>(krow + c * 8);
        float kf[8];
#pragma unroll
        for (int j = 0; j < 8; ++j) kf[j] = (float)kvv[j];
#pragma unroll
        for (int m = 0; m < 8; ++m) {
            const float* qrow = &qs[m * 128 + half * 64 + c * 8];
            float aa = 0.f;
#pragma unroll
            for (int j = 0; j < 8; ++j) aa += kf[j] * qrow[j];
            acc[m] += aa;
        }
    }
#pragma unroll
    for (int m = 0; m < 8; ++m) acc[m] += __shfl_xor(acc[m], 1);
    float mx = acc[0];
#pragma unroll
    for (int m = 1; m < 8; ++m) mx = fmaxf(mx, acc[m]);
    float e[8]; float ssum = 0.f;
#pragma unroll
    for (int m = 0; m < 8; ++m) { e[m] = __expf(acc[m] - mx); ssum += e[m]; }
    float inv = 1.0f / ssum;
    float a8[8];
#pragma unroll
    for (int m = 0; m < 8; ++m) a8[m] = e[m] * inv + ATTN_EPS;
    *reinterpret_cast<float4*>(&at[nl][half * 4]) =
        make_float4(a8[half * 4], a8[half * 4 + 1], a8[half * 4 + 2], a8[half * 4 + 3]);
#pragma unroll
    for (int m = 0; m < 8; ++m) {
        float v = a8[m];
#pragma unroll
        for (int off = 32; off > 0; off >>= 1) v += __shfl_xor(v, off);
        if (lane == 0) colpart[wv][m] = v * 0.5f;
    }
    __syncthreads();
    const int m2 = t >> 5;
    const int s0 = (t & 31) * 4;
    float a0 = 0.f, a1 = 0.f, a2 = 0.f, a3 = 0.f;
#pragma unroll 4
    for (int n = 0; n < 128; ++n) {
        float a = at[n][m2];
        v4bf vvv = *reinterpret_cast<const v4bf*>(&vt[n][s0]);
        a0 += a * (float)vvv[0];
        a1 += a * (float)vvv[1];
        a2 += a * (float)vvv[2];
        a3 += a * (float)vvv[3];
    }
    *reinterpret_cast<float4*>(upd_part + ((size_t)(b * 32 + ch) * 8 + m2) * 128 + s0) =
        make_float4(a0, a1, a2, a3);
    if (t < 8)
        colsum_part[(b * 32 + ch) * 8 + t] =
            colpart[0][t] + colpart[1][t] + colpart[2][t] + colpart[3][t];
}

// ---------------------------------------------------------------------------
// Kernel 5: reduce partials, GRU, LN, MLP -> new slots; next-iter q.
// 256 threads: (tid, half) split-K halves the serial fma chains; 4 waves.
// ---------------------------------------------------------------------------
__global__ __launch_bounds__(256) void k_finishq(const float* __restrict__ upd_part,
                                                 const float* __restrict__ colsum_part,
                                                 const float* __restrict__ slots_in,
                                                 const float* __restrict__ Wih, const float* __restrict__ Whh,
                                                 const float* __restrict__ bih, const float* __restrict__ bhh,
                                                 const float* __restrict__ lnw, const float* __restrict__ lnb,
                                                 const float* __restrict__ W1, const float* __restrict__ b1,
                                                 const float* __restrict__ W2, const float* __restrict__ b2,
                                                 const float* __restrict__ lnsw, const float* __restrict__ lnsb,
                                                 const float* __restrict__ Wq,
                                                 float* __restrict__ slots_out, float* __restrict__ qout) {
    __shared__ float us[128], sp[128], hnorm[128], qsrc[128], act[256];
    __shared__ float upart[2][128];
    __shared__ float gpart[2][6][128];
    __shared__ float p2[2][128];
    __shared__ float qpart[2][128];
    __shared__ float red[4];
    __shared__ float csum_sh;
    const int t   = threadIdx.x;
    const int tid = t & 127, half = t >> 7;
    const int bm  = blockIdx.x;
    const int b = bm >> 3, m = bm & 7;
    if (t < 64) {
        float v = (t < 32) ? colsum_part[(b * 32 + t) * 8 + m] : 0.f;
#pragma unroll
        for (int off = 32; off > 0; off >>= 1) v += __shfl_xor(v, off);
        if (t == 0) csum_sh = v;
    }
    float u = 0.f;
#pragma unroll 4
    for (int chk = half * 16; chk < half * 16 + 16; ++chk)
        u += upd_part[((size_t)(b * 32 + chk) * 8 + m) * 128 + tid];
    upart[half][tid] = u;
    if (half == 0) sp[tid] = slots_in[bm * 128 + tid];
    __syncthreads();
    if (half == 0) us[tid] = (upart[0][tid] + upart[1][tid]) * (1.f / csum_sh);
    __syncthreads();
    // ---- GRU partial dots (split-K over halves)
    {
        const int d0g = half * 64;
        float a_r = 0.f, a_z = 0.f, a_n = 0.f, b_r = 0.f, b_z = 0.f, b_n = 0.f;
        const float* Wr = Wih + (size_t)tid * 128 + d0g;
        const float* Wz = Wih + (size_t)(128 + tid) * 128 + d0g;
        const float* Wn = Wih + (size_t)(256 + tid) * 128 + d0g;
        const float* Vr = Whh + (size_t)tid * 128 + d0g;
        const float* Vz = Whh + (size_t)(128 + tid) * 128 + d0g;
        const float* Vn = Whh + (size_t)(256 + tid) * 128 + d0g;
#pragma unroll 4
        for (int d = 0; d < 64; d += 4) {
            float u0 = us[d0g + d], u1 = us[d0g + d + 1], u2 = us[d0g + d + 2], u3 = us[d0g + d + 3];
            float p0 = sp[d0g + d], p1 = sp[d0g + d + 1], p2_ = sp[d0g + d + 2], p3 = sp[d0g + d + 3];
            float4 w;
            w = *reinterpret_cast<const float4*>(Wr + d); a_r += w.x*u0 + w.y*u1 + w.z*u2 + w.w*u3;
            w = *reinterpret_cast<const float4*>(Wz + d); a_z += w.x*u0 + w.y*u1 + w.z*u2 + w.w*u3;
            w = *reinterpret_cast<const float4*>(Wn + d); a_n += w.x*u0 + w.y*u1 + w.z*u2 + w.w*u3;
            w = *reinterpret_cast<const float4*>(Vr + d); b_r += w.x*p0 + w.y*p1 + w.z*p2_ + w.w*p3;
            w = *reinterpret_cast<const float4*>(Vz + d); b_z += w.x*p0 + w.y*p1 + w.z*p2_ + w.w*p3;
            w = *reinterpret_cast<const float4*>(Vn + d); b_n += w.x*p0 + w.y*p1 + w.z*p2_ + w.w*p3;
        }
        gpart[half][0][tid] = a_r; gpart[half][1][tid] = a_z; gpart[half][2][tid] = a_n;
        gpart[half][3][tid] = b_r; gpart[half][4][tid] = b_z; gpart[half][5][tid] = b_n;
    }
    __syncthreads();
    float gir = bih[tid]       + gpart[0][0][tid] + gpart[1][0][tid];
    float giz = bih[128 + tid] + gpart[0][1][tid] + gpart[1][1][tid];
    float gin = bih[256 + tid] + gpart[0][2][tid] + gpart[1][2][tid];
    float ghr = bhh[tid]       + gpart[0][3][tid] + gpart[1][3][tid];
    float ghz = bhh[128 + tid] + gpart[0][4][tid] + gpart[1][4][tid];
    float ghn = bhh[256 + tid] + gpart[0][5][tid] + gpart[1][5][tid];
    float h0 = sp[tid];
    float r  = 1.f / (1.f + __expf(-(gir + ghr)));
    float z  = 1.f / (1.f + __expf(-(giz + ghz)));
    float nn = tanhf(gin + r * ghn);
    float h  = (1.f - z) * nn + z * h0;
    // ---- LN(h)
    if (half == 0) {
        float s = h, s2 = h * h;
#pragma unroll
        for (int off = 32; off > 0; off >>= 1) { s += __shfl_xor(s, off); s2 += __shfl_xor(s2, off); }
        if ((t & 63) == 0) { red[(tid >> 6) * 2] = s; red[(tid >> 6) * 2 + 1] = s2; }
    }
    __syncthreads();
    {
        float S1 = red[0] + red[2], S2 = red[1] + red[3];
        float mean = S1 * (1.f / Ss);
        float rstd = rsqrtf(S2 * (1.f / Ss) - mean * mean + LN_EPS_F);
        if (half == 0) hnorm[tid] = (h - mean) * rstd * lnw[tid] + lnb[tid];
    }
    __syncthreads();
    // ---- MLP1
    {
        float a = b1[t];
        const float* w1r = W1 + (size_t)t * 128;
#pragma unroll 4
        for (int d = 0; d < 128; d += 4) {
            float4 w = *reinterpret_cast<const float4*>(w1r + d);
            a += w.x * hnorm[d] + w.y * hnorm[d + 1] + w.z * hnorm[d + 2] + w.w * hnorm[d + 3];
        }
        act[t] = fmaxf(a, 0.f);
    }
    __syncthreads();
    // ---- MLP2 split-K
    {
        float o = 0.f;
        const int j0 = half * 128;
        const float* w2r = W2 + (size_t)tid * 256 + j0;
#pragma unroll 4
        for (int j = 0; j < 128; j += 4) {
            float4 w = *reinterpret_cast<const float4*>(w2r + j);
            o += w.x * act[j0 + j] + w.y * act[j0 + j + 1] + w.z * act[j0 + j + 2] + w.w * act[j0 + j + 3];
        }
        p2[half][tid] = o;
    }
    __syncthreads();
    float snew = h + b2[tid] + p2[0][tid] + p2[1][tid];
    if (half == 0) slots_out[bm * 128 + tid] = snew;
    // ---- next-iter q
    if (half == 0) {
        float s = snew, s2 = snew * snew;
#pragma unroll
        for (int off = 32; off > 0; off >>= 1) { s += __shfl_xor(s, off); s2 += __shfl_xor(s2, off); }
        if ((t & 63) == 0) { red[(tid >> 6) * 2] = s; red[(tid >> 6) * 2 + 1] = s2; }
    }
    __syncthreads();
    {
        float T1 = red[0] + red[2], T2 = red[1] + red[3];
        float m2 = T1 * (1.f / Ss);
        float rstd2 = rsqrtf(T2 * (1.f / Ss) - m2 * m2 + LN_EPS_F);
        if (half == 0) qsrc[tid] = (snew - m2) * rstd2 * lnsw[tid] + lnsb[tid];
    }
    __syncthreads();
    {
        float qa = 0.f;
        const int d0g = half * 64;
        const float* wr = Wq + (size_t)tid * 128 + d0g;
#pragma unroll 4
        for (int d = 0; d < 64; d += 4) {
            float4 w = *reinterpret_cast<const float4*>(wr + d);
            qa += w.x * qsrc[d0g + d] + w.y * qsrc[d0g + d + 1] + w.z * qsrc[d0g + d + 2] + w.w * qsrc[d0g + d + 3];
        }
        qpart[half][tid] = qa;
    }
    __syncthreads();
    if (half == 0)
        qout[bm * 128 + tid] = (qpart[0][tid] + qpart[1][tid]) * 0.08838834764831845f;
}

// ---------------------------------------------------------------------------
extern "C" void kernel_launch(void* const* d_in, const int* in_sizes, int n_in,
                              void* d_out, int out_size, void* d_ws, size_t ws_size,
                              hipStream_t stream) {
    const float* X          = (const float*)d_in[0];
    const float* slots_init = (const float*)d_in[1];
    const float* ln_in_w    = (const float*)d_in[2];
    const float* ln_in_b    = (const float*)d_in[3];
    const float* ln_slot_w  = (const float*)d_in[4];
    const float* ln_slot_b  = (const float*)d_in[5];
    const float* ln_mlp_w   = (const float*)d_in[6];
    const float* ln_mlp_b   = (const float*)d_in[7];
    const float* Wq         = (const float*)d_in[8];
    const float* Wk         = (const float*)d_in[9];
    const float* Wv         = (const float*)d_in[10];
    const float* gWih       = (const float*)d_in[11];
    const float* gWhh       = (const float*)d_in[12];
    const float* gbih       = (const float*)d_in[13];
    const float* gbhh       = (const float*)d_in[14];
    const float* W1         = (const float*)d_in[15];
    const float* b1         = (const float*)d_in[16];
    const float* W2         = (const float*)d_in[17];
    const float* b2         = (const float*)d_in[18];
    const float* mu         = (const float*)d_in[19];
    const float* lsig       = (const float*)d_in[20];

    char* p = (char*)d_ws;
    u16*    Wkvp        = (u16*)p;    p += (size_t)256 * 512 * sizeof(u16);           // 256 KB
    float*  cb          = (float*)p;  p += 256 * sizeof(float);
    float*  Scol        = (float*)p;  p += 256 * sizeof(float);
    float*  slots       = (float*)p;  p += 32 * 8 * 128 * sizeof(float);              // 128 KB
    float*  qbuf        = (float*)p;  p += 32 * 8 * 128 * sizeof(float);              // 128 KB
    float*  colsum_part = (float*)p;  p += 32 * 32 * 8 * sizeof(float);               // 32 KB
    float*  upd_part    = (float*)p;  p += (size_t)32 * 32 * 8 * 128 * sizeof(float); // 4 MB
    u16*    kv          = (u16*)p;    p += (size_t)MROWS * 256 * sizeof(u16);         // 67 MB
    u16*    Xb          = (u16*)p;    p += (size_t)MROWS * Dd * sizeof(u16);          // 134 MB
    float2* stats       = (float2*)p; p += (size_t)MROWS * sizeof(float2);            // 1 MB

    k_cast<<<MROWS / 4, 256, 0, stream>>>(X, Xb, stats);
    k_prep<<<648, 256, 0, stream>>>(Wk, Wv, ln_in_w, ln_in_b, slots_init, mu, lsig,
                                    Wkvp, cb, Scol, slots);
    k_kvgemm<<<dim3(MROWS / 128, 2), 256, 0, stream>>>(Xb, stats, Wkvp, cb, Scol, kv);
    k_q<<<256, 128, 0, stream>>>(slots, ln_slot_w, ln_slot_b, Wq, qbuf);

    for (int it = 0; it < 3; ++it) {
        k_attnupd<<<dim3(32, 32), 256, 0, stream>>>(kv, qbuf, upd_part, colsum_part);
        k_finishq<<<256, 256, 0, stream>>>(upd_part, colsum_part, slots,
                                           gWih, gWhh, gbih, gbhh,
                                           ln_mlp_w, ln_mlp_b, W1, b1, W2, b2,
                                           ln_slot_w, ln_slot_b, Wq,
                                           (it == 2) ? (float*)d_out : slots, qbuf);
    }
}